// Round 1
// baseline (762.453 us; speedup 1.0000x reference)
//
#include <hip/hip_runtime.h>
#include <cstddef>

#define SEQLEN 32
#define BATCH  32768
#define POSE   34
#define HDIM   16
#define PREDL  15

// fast device activations: fp32, HW exp/rcp (errors ~1e-6, threshold is 1e-2)
__device__ __forceinline__ float sigm(float x) {
    return __builtin_amdgcn_rcpf(1.0f + __expf(-x));
}
__device__ __forceinline__ float tanh_(float x) {
    // tanh(x) = 2*sigmoid(2x) - 1
    return fmaf(2.0f, __builtin_amdgcn_rcpf(1.0f + __expf(-2.0f * x)), -1.0f);
}

// 16 gate pre-activations for rows [16w, 16w+16).  w is wave-uniform ->
// every weight/bias index is uniform -> compiler emits scalar (s_load)
// reads and the loop body is pure v_fma_f32 (SGPR weight operand).
__device__ __forceinline__ void gates16(
    float acc[16],
    const float* __restrict__ Wih, const float* __restrict__ Whh,
    const float* __restrict__ bih, const float* __restrict__ bhh,
    int w, const float xv[POSE], const float hv[HDIM])
{
#pragma unroll
    for (int r = 0; r < 16; ++r) {
        const int row = 16 * w + r;
        float a = bih[row] + bhh[row];
#pragma unroll
        for (int k = 0; k < POSE; ++k) a = fmaf(Wih[row * POSE + k], xv[k], a);
#pragma unroll
        for (int k = 0; k < HDIM; ++k) a = fmaf(Whh[row * HDIM + k], hv[k], a);
        acc[r] = a;
    }
}

// Shared LSTM pointwise stage: activate own gate chunk, exchange via LDS,
// update the 4 owned c dims, rebuild replicated h[16].
// gate order (torch): w0=i, w1=f, w2=g(tanh), w3=o.
__device__ __forceinline__ void cell_update(
    int w, int lane, float acc[16],
    float (&gate_lds)[4][64][17], float (&h_lds)[64][17],
    float cown[4], float hv[HDIM])
{
#pragma unroll
    for (int r = 0; r < 16; ++r)
        acc[r] = (w == 2) ? tanh_(acc[r]) : sigm(acc[r]);   // w uniform branch
#pragma unroll
    for (int r = 0; r < 16; ++r) gate_lds[w][lane][r] = acc[r];
    __syncthreads();
#pragma unroll
    for (int d = 0; d < 4; ++d) {
        const int dim = 4 * w + d;
        const float iv = gate_lds[0][lane][dim];
        const float fv = gate_lds[1][lane][dim];
        const float gv = gate_lds[2][lane][dim];
        const float ov = gate_lds[3][lane][dim];
        const float c  = fmaf(fv, cown[d], iv * gv);
        cown[d] = c;
        h_lds[lane][dim] = ov * tanh_(c);
    }
    __syncthreads();
#pragma unroll
    for (int k = 0; k < HDIM; ++k) hv[k] = h_lds[lane][k];
}

extern "C" __global__ void __launch_bounds__(256, 2) lstm_fused(
    const float* __restrict__ obs_s,
    const float* __restrict__ eWih, const float* __restrict__ eWhh,
    const float* __restrict__ ebih, const float* __restrict__ ebhh,
    const float* __restrict__ dWih, const float* __restrict__ dWhh,
    const float* __restrict__ dbih, const float* __restrict__ dbhh,
    const float* __restrict__ cWih, const float* __restrict__ cWhh,
    const float* __restrict__ cbih, const float* __restrict__ cbhh,
    const float* __restrict__ fcW,  const float* __restrict__ fcb,
    const float* __restrict__ fccW, const float* __restrict__ fccb,
    const float* __restrict__ mlpW, const float* __restrict__ mlpb,
    const float* __restrict__ embW, const float* __restrict__ embb,
    float* __restrict__ out_s, float* __restrict__ out_cr)
{
    __shared__ float x_tile[64][35];        // padded: conflict-free strided reads
    __shared__ float gate_lds[4][64][17];
    __shared__ float h_lds[64][17];
    __shared__ float s_lds[64][35];

    const int tid  = threadIdx.x;
    const int lane = tid & 63;
    const int w    = __builtin_amdgcn_readfirstlane(tid >> 6); // force SGPR
    const int b0   = blockIdx.x * 64;

    float h[HDIM], cown[4];
#pragma unroll
    for (int k = 0; k < HDIM; ++k) h[k] = 0.0f;
#pragma unroll
    for (int d = 0; d < 4; ++d) cown[d] = 0.0f;

    float x[POSE];
    float acc[16];

    // ---------------- encoder: 32 steps ----------------
    for (int t = 0; t < SEQLEN; ++t) {
        const float* src = obs_s + ((size_t)t * BATCH + b0) * POSE;
        for (int i = tid; i < 64 * POSE; i += 256)
            x_tile[i / POSE][i % POSE] = src[i];       // coalesced coop load
        __syncthreads();
#pragma unroll
        for (int k = 0; k < POSE; ++k) x[k] = x_tile[lane][k];
        gates16(acc, eWih, eWhh, ebih, ebhh, w, x, h);
        cell_update(w, lane, acc, gate_lds, h_lds, cown, h);
    }

    // ---------------- decoder init ----------------
    float last_s[POSE], last_cr[POSE];
#pragma unroll
    for (int k = 0; k < POSE; ++k) { last_s[k] = x[k]; last_cr[k] = x[k]; }

    float hc[HDIM], ccown[4];
#pragma unroll
    for (int j = 0; j < HDIM; ++j) {
        float a = mlpb[j];
#pragma unroll
        for (int k = 0; k < HDIM; ++k) a = fmaf(mlpW[j * HDIM + k], h[k], a);
        hc[j] = a;                                     // redundant across waves
    }
#pragma unroll
    for (int d = 0; d < 4; ++d) ccown[d] = 0.0f;

    // ---------------- decoder: 15 steps ----------------
    for (int s = 0; s < PREDL; ++s) {
        // crossing cell
        gates16(acc, cWih, cWhh, cbih, cbhh, w, last_cr, hc);
        cell_update(w, lane, acc, gate_lds, h_lds, ccown, hc);

        // curr_cr = softmax(hc @ fccW.T + fccb)   (redundant per wave, tiny)
        float z0 = fccb[0], z1 = fccb[1];
#pragma unroll
        for (int k = 0; k < HDIM; ++k) {
            z0 = fmaf(fccW[k],        hc[k], z0);
            z1 = fmaf(fccW[HDIM + k], hc[k], z1);
        }
        const float m  = fmaxf(z0, z1);
        const float e0 = __expf(z0 - m), e1 = __expf(z1 - m);
        const float rs = __builtin_amdgcn_rcpf(e0 + e1);
        const float p0 = e0 * rs, p1 = e1 * rs;

        // next_cr = curr_cr @ embW.T + embb  -> becomes last_cr (dead by now)
#pragma unroll
        for (int j = 0; j < POSE; ++j)
            last_cr[j] = fmaf(p0, embW[2 * j], fmaf(p1, embW[2 * j + 1], embb[j]));

        // decoder cell
        gates16(acc, dWih, dWhh, dbih, dbhh, w, last_s, h);
        cell_update(w, lane, acc, gate_lds, h_lds, cown, h);

        // curr_s = h @ fcW.T + fcb : rows split across the 4 waves
#pragma unroll
        for (int jj = 0; jj < 9; ++jj) {
            const int j = w * 9 + jj;                  // uniform guard
            if (j < POSE) {
                float a = fcb[j];
#pragma unroll
                for (int k = 0; k < HDIM; ++k) a = fmaf(fcW[j * HDIM + k], h[k], a);
                s_lds[lane][j] = a;
            }
        }
        __syncthreads();
#pragma unroll
        for (int j = 0; j < POSE; ++j) last_s[j] = s_lds[lane][j];

        // outputs: wave 0 writes (values replicated)
        if (w == 0) {
            float* ps = out_s + ((size_t)s * BATCH + b0 + lane) * POSE;
#pragma unroll
            for (int j = 0; j < POSE; j += 2)
                *(float2*)(ps + j) = make_float2(last_s[j], last_s[j + 1]);
            *(float2*)(out_cr + ((size_t)s * BATCH + b0 + lane) * 2) =
                make_float2(p0, p1);
        }
    }
}

extern "C" void kernel_launch(void* const* d_in, const int* in_sizes, int n_in,
                              void* d_out, int out_size, void* d_ws, size_t ws_size,
                              hipStream_t stream)
{
    const float* obs  = (const float*)d_in[0];
    const float* eWih = (const float*)d_in[1];
    const float* eWhh = (const float*)d_in[2];
    const float* ebih = (const float*)d_in[3];
    const float* ebhh = (const float*)d_in[4];
    const float* dWih = (const float*)d_in[5];
    const float* dWhh = (const float*)d_in[6];
    const float* dbih = (const float*)d_in[7];
    const float* dbhh = (const float*)d_in[8];
    const float* cWih = (const float*)d_in[9];
    const float* cWhh = (const float*)d_in[10];
    const float* cbih = (const float*)d_in[11];
    const float* cbhh = (const float*)d_in[12];
    const float* fcW  = (const float*)d_in[13];
    const float* fcb  = (const float*)d_in[14];
    const float* fccW = (const float*)d_in[15];
    const float* fccb = (const float*)d_in[16];
    const float* mlpW = (const float*)d_in[17];
    const float* mlpb = (const float*)d_in[18];
    const float* embW = (const float*)d_in[19];
    const float* embb = (const float*)d_in[20];

    float* out_s  = (float*)d_out;
    float* out_cr = out_s + (size_t)PREDL * BATCH * POSE;

    dim3 grid(BATCH / 64), block(256);
    hipLaunchKernelGGL(lstm_fused, grid, block, 0, stream,
                       obs, eWih, eWhh, ebih, ebhh, dWih, dWhh, dbih, dbhh,
                       cWih, cWhh, cbih, cbhh, fcW, fcb, fccW, fccb,
                       mlpW, mlpb, embW, embb, out_s, out_cr);
}

// Round 2
// 96.558 us; speedup vs baseline: 7.8963x; 7.8963x over previous
//
#include <hip/hip_runtime.h>
#include <cstddef>

#define SEQLEN 32
#define BATCH  32768
#define POSE   34
#define HDIM   16
#define PREDL  15

typedef __attribute__((ext_vector_type(8))) short short8;
typedef __attribute__((ext_vector_type(4))) float f32x4;

__device__ __forceinline__ float sigm(float x) {
    return __builtin_amdgcn_rcpf(1.0f + __expf(-x));
}
__device__ __forceinline__ float tanh_(float x) {
    return fmaf(2.0f, __builtin_amdgcn_rcpf(1.0f + __expf(-2.0f * x)), -1.0f);
}
__device__ __forceinline__ unsigned short f2bf(float f) {
    union { float f; unsigned u; } x; x.f = f;
    unsigned r = x.u + 0x7FFFu + ((x.u >> 16) & 1u);
    return (unsigned short)(r >> 16);
}

// gates[16b x 64g] = A(x|h) * Wt + bias ; acc[gt] laid out as D: b=(lane>>4)*4+j, d=lane&15
__device__ __forceinline__ void gates_mfma(
    const unsigned short (&Wt)[4][16][72], const float* bias,
    short8 a0, short8 a1, int lo, int g, f32x4 acc[4])
{
#pragma unroll
    for (int gt = 0; gt < 4; ++gt) {
        float bv = bias[gt * 16 + lo];
        f32x4 c = {bv, bv, bv, bv};
        short8 b0 = *(const short8*)&Wt[gt][lo][8 * g];
        c = __builtin_amdgcn_mfma_f32_16x16x32_bf16(a0, b0, c, 0, 0, 0);
        short8 b1 = *(const short8*)&Wt[gt][lo][32 + 8 * g];
        c = __builtin_amdgcn_mfma_f32_16x16x32_bf16(a1, b1, c, 0, 0, 0);
        acc[gt] = c;
    }
}

// i,f,g,o pointwise; c in fp32 regs; returns h (fp32)
__device__ __forceinline__ void cell_pointwise(const f32x4 acc[4], float cst[4], float hv[4])
{
#pragma unroll
    for (int j = 0; j < 4; ++j) {
        float iv = sigm(acc[0][j]);
        float fv = sigm(acc[1][j]);
        float gv = tanh_(acc[2][j]);
        float ov = sigm(acc[3][j]);
        float cn = fmaf(fv, cst[j], iv * gv);
        cst[j] = cn;
        hv[j] = ov * tanh_(cn);
    }
}

extern "C" __global__ void __launch_bounds__(256, 2) lstm_mfma(
    const float* __restrict__ obs_s,
    const float* __restrict__ eWih, const float* __restrict__ eWhh,
    const float* __restrict__ ebih, const float* __restrict__ ebhh,
    const float* __restrict__ dWih, const float* __restrict__ dWhh,
    const float* __restrict__ dbih, const float* __restrict__ dbhh,
    const float* __restrict__ cWih, const float* __restrict__ cWhh,
    const float* __restrict__ cbih, const float* __restrict__ cbhh,
    const float* __restrict__ fcW,  const float* __restrict__ fcb,
    const float* __restrict__ fccW, const float* __restrict__ fccb,
    const float* __restrict__ mlpW, const float* __restrict__ mlpb,
    const float* __restrict__ embW, const float* __restrict__ embb,
    float* __restrict__ out_s, float* __restrict__ out_cr)
{
    // K layout per row (80 bf16, 160B): [x:0..34)[pad:34..40)[h:40..56)[zero:56..80)
    __shared__ unsigned short WtU[3][4][16][72];   // [cell][gate-tile][n][k] (72-pad: 2-way banks)
    __shared__ unsigned short fcWtU[3][16][40];    // fc head B tiles (k>=16 zero)
    __shared__ unsigned short mlpWtU[16][40];
    __shared__ unsigned short XaU[4][2][16 * 80];  // [wave][0=enc/dec,1=cr][b*80+k]
    __shared__ float biasL[3][64];
    __shared__ float fcbL[48];
    __shared__ float mlpbL[16];
    __shared__ float fccL[32];
    __shared__ float embtL[40][4];                 // {embW[k][0], embW[k][1], embb[k], 0}
    __shared__ float2 pbuf[4][16];

    const int tid  = threadIdx.x;
    const int lane = tid & 63;
    const int wv   = tid >> 6;
    const int lo   = lane & 15;   // A-frag row (batch) / D col (hidden dim) / B col
    const int g    = lane >> 4;   // k-group
    const int wb   = blockIdx.x * 64 + wv * 16;   // this wave's batch base

    // ---------------- one-time staging ----------------
    {
        const float* WihA[3] = {eWih, dWih, cWih};
        const float* WhhA[3] = {eWhh, dWhh, cWhh};
        const float* bihA[3] = {ebih, dbih, cbih};
        const float* bhhA[3] = {ebhh, dbhh, cbhh};
        for (int c = 0; c < 3; ++c) {
            for (int idx = tid; idx < 4 * 16 * 72; idx += 256) {
                int k = idx % 72, rem = idx / 72;
                int n = rem & 15, gt = rem >> 4;
                int row = gt * 16 + n;
                float v = 0.f;
                if (k < 34) v = WihA[c][row * 34 + k];
                else if (k >= 40 && k < 56) v = WhhA[c][row * 16 + (k - 40)];
                WtU[c][gt][n][k] = f2bf(v);
            }
            if (tid < 64) biasL[c][tid] = bihA[c][tid] + bhhA[c][tid];
        }
        for (int idx = tid; idx < 3 * 16 * 40; idx += 256) {
            int k = idx % 40, rem = idx / 40;
            int n = rem & 15, nt = rem >> 4;
            int rowp = nt * 16 + n;
            float v = (k < 16 && rowp < 34) ? fcW[rowp * 16 + k] : 0.f;
            fcWtU[nt][n][k] = f2bf(v);
        }
        for (int idx = tid; idx < 16 * 40; idx += 256) {
            int k = idx % 40, n = idx / 40;
            mlpWtU[n][k] = f2bf((k < 16) ? mlpW[n * 16 + k] : 0.f);
        }
        if (tid < 48) fcbL[tid] = (tid < 34) ? fcb[tid] : 0.f;
        if (tid < 16) mlpbL[tid] = mlpb[tid];
        if (tid < 32) fccL[tid] = fccW[tid];
        for (int idx = tid; idx < 160; idx += 256) {
            int k = idx >> 2, cp = idx & 3;
            float v = 0.f;
            if (k < 34) {
                if (cp == 0) v = embW[2 * k];
                else if (cp == 1) v = embW[2 * k + 1];
                else if (cp == 2) v = embb[k];
            }
            embtL[k][cp] = v;
        }
        for (int idx = tid; idx < 4 * 2 * 1280; idx += 256)
            ((unsigned short*)XaU)[idx] = 0;
    }
    __syncthreads();   // only barrier in the kernel; waves are independent after this

    unsigned short* XaD = &XaU[wv][0][0];
    unsigned short* XaC = &XaU[wv][1][0];

    float cst[4] = {0.f, 0.f, 0.f, 0.f};   // decoder/encoder c

    // ---------------- encoder (32 steps), x software-prefetched ----------------
    const float* srcbase = obs_s + (size_t)wb * POSE;
    {   // stage t=0
        const float* s0 = srcbase;
#pragma unroll
        for (int it = 0; it < 9; ++it) {
            int idx = lane + it * 64;
            if (idx < 544) {
                int b = idx / 34, k = idx - b * 34;
                XaD[b * 80 + k] = f2bf(s0[idx]);
            }
        }
    }
    for (int t = 0; t < SEQLEN; ++t) {
        float xr[9];
        if (t + 1 < SEQLEN) {
            const float* s1 = srcbase + (size_t)(t + 1) * BATCH * POSE;
#pragma unroll
            for (int it = 0; it < 9; ++it) {
                int idx = lane + it * 64;
                xr[it] = (idx < 544) ? s1[idx] : 0.f;
            }
        }
        short8 a0 = *(const short8*)&XaD[lo * 80 + 8 * g];
        short8 a1 = *(const short8*)&XaD[lo * 80 + 32 + 8 * g];
        f32x4 acc[4];
        gates_mfma(WtU[0], biasL[0], a0, a1, lo, g, acc);
        float hv[4];
        cell_pointwise(acc, cst, hv);
#pragma unroll
        for (int j = 0; j < 4; ++j)
            XaD[(g * 4 + j) * 80 + 40 + lo] = f2bf(hv[j]);
        if (t + 1 < SEQLEN) {
#pragma unroll
            for (int it = 0; it < 9; ++it) {
                int idx = lane + it * 64;
                if (idx < 544) {
                    int b = idx / 34, k = idx - b * 34;
                    XaD[b * 80 + k] = f2bf(xr[it]);
                }
            }
        }
    }

    // ---------------- hc = mlp(h), cc = 0 ----------------
    float cc[4] = {0.f, 0.f, 0.f, 0.f};
    {
        short8 ah = *(const short8*)&XaD[lo * 80 + 40 + 8 * g];
        float bv = mlpbL[lo];
        f32x4 o = {bv, bv, bv, bv};
        short8 bm = *(const short8*)&mlpWtU[lo][8 * g];
        o = __builtin_amdgcn_mfma_f32_16x16x32_bf16(ah, bm, o, 0, 0, 0);
#pragma unroll
        for (int j = 0; j < 4; ++j)
            XaC[(g * 4 + j) * 80 + 40 + lo] = f2bf(o[j]);
    }

    const float fb0 = fccb[0], fb1 = fccb[1];
    const float w0 = fccL[lo], w1 = fccL[16 + lo];

    // ---------------- decoder (15 steps) ----------------
    for (int s = 0; s < PREDL; ++s) {
        // ---- crossing cell A-fragments ----
        short8 a0c, a1c;
        a1c = *(const short8*)&XaC[lo * 80 + 32 + 8 * g];  // [32..40)=0, [40..56)=hc, rest 0
        if (s == 0) {
            a0c = *(const short8*)&XaD[lo * 80 + 8 * g];   // obs[-1]
            if (g == 0) {
                a1c[0] = (short)XaD[lo * 80 + 32];
                a1c[1] = (short)XaD[lo * 80 + 33];
            }
        } else {
            float2 pv = pbuf[wv][lo];
#pragma unroll
            for (int e = 0; e < 8; ++e) {
                int k = 8 * g + e;
                f32x4 em = *(const f32x4*)&embtL[k][0];
                a0c[e] = (short)f2bf(fmaf(pv.x, em[0], fmaf(pv.y, em[1], em[2])));
            }
            if (g == 0) {
                f32x4 e32 = *(const f32x4*)&embtL[32][0];
                f32x4 e33 = *(const f32x4*)&embtL[33][0];
                a1c[0] = (short)f2bf(fmaf(pv.x, e32[0], fmaf(pv.y, e32[1], e32[2])));
                a1c[1] = (short)f2bf(fmaf(pv.x, e33[0], fmaf(pv.y, e33[1], e33[2])));
            }
        }
        f32x4 acc[4];
        gates_mfma(WtU[2], biasL[2], a0c, a1c, lo, g, acc);
        float hcv[4];
        cell_pointwise(acc, cc, hcv);
#pragma unroll
        for (int j = 0; j < 4; ++j)
            XaC[(g * 4 + j) * 80 + 40 + lo] = f2bf(hcv[j]);

        // ---- z = hc @ fccW.T + fccb ; softmax (16-lane shuffle reduce over d=lo) ----
        float p0[4], p1[4];
#pragma unroll
        for (int j = 0; j < 4; ++j) {
            float z0 = hcv[j] * w0, z1 = hcv[j] * w1;
#pragma unroll
            for (int m = 1; m < 16; m <<= 1) {
                z0 += __shfl_xor(z0, m);
                z1 += __shfl_xor(z1, m);
            }
            z0 += fb0; z1 += fb1;
            float mx = fmaxf(z0, z1);
            float e0 = __expf(z0 - mx), e1 = __expf(z1 - mx);
            float rs = __builtin_amdgcn_rcpf(e0 + e1);
            p0[j] = e0 * rs; p1[j] = e1 * rs;
        }
        if (lo == 0) {
#pragma unroll
            for (int j = 0; j < 4; ++j) {
                int b = g * 4 + j;
                pbuf[wv][b] = make_float2(p0[j], p1[j]);
                *(float2*)(out_cr + ((size_t)s * BATCH + wb + b) * 2) =
                    make_float2(p0[j], p1[j]);
            }
        }

        // ---- decoder cell ----
        short8 a0d = *(const short8*)&XaD[lo * 80 + 8 * g];
        short8 a1d = *(const short8*)&XaD[lo * 80 + 32 + 8 * g];
        f32x4 accd[4];
        gates_mfma(WtU[1], biasL[1], a0d, a1d, lo, g, accd);
        float hv[4];
        cell_pointwise(accd, cst, hv);
#pragma unroll
        for (int j = 0; j < 4; ++j)
            XaD[(g * 4 + j) * 80 + 40 + lo] = f2bf(hv[j]);

        // ---- fc head: curr_s = h @ fcW.T + fcb ; write out + feed back as last_s ----
        short8 ah = *(const short8*)&XaD[lo * 80 + 40 + 8 * g];
#pragma unroll
        for (int nt = 0; nt < 3; ++nt) {
            float bv = fcbL[nt * 16 + lo];
            f32x4 o = {bv, bv, bv, bv};
            short8 bw = *(const short8*)&fcWtU[nt][lo][8 * g];
            o = __builtin_amdgcn_mfma_f32_16x16x32_bf16(ah, bw, o, 0, 0, 0);
            int np = nt * 16 + lo;
            if (np < POSE) {
#pragma unroll
                for (int j = 0; j < 4; ++j) {
                    int b = g * 4 + j;
                    out_s[((size_t)s * BATCH + wb + b) * POSE + np] = o[j];
                    XaD[b * 80 + np] = f2bf(o[j]);
                }
            }
        }
    }
}

extern "C" void kernel_launch(void* const* d_in, const int* in_sizes, int n_in,
                              void* d_out, int out_size, void* d_ws, size_t ws_size,
                              hipStream_t stream)
{
    const float* obs  = (const float*)d_in[0];
    const float* eWih = (const float*)d_in[1];
    const float* eWhh = (const float*)d_in[2];
    const float* ebih = (const float*)d_in[3];
    const float* ebhh = (const float*)d_in[4];
    const float* dWih = (const float*)d_in[5];
    const float* dWhh = (const float*)d_in[6];
    const float* dbih = (const float*)d_in[7];
    const float* dbhh = (const float*)d_in[8];
    const float* cWih = (const float*)d_in[9];
    const float* cWhh = (const float*)d_in[10];
    const float* cbih = (const float*)d_in[11];
    const float* cbhh = (const float*)d_in[12];
    const float* fcW  = (const float*)d_in[13];
    const float* fcb  = (const float*)d_in[14];
    const float* fccW = (const float*)d_in[15];
    const float* fccb = (const float*)d_in[16];
    const float* mlpW = (const float*)d_in[17];
    const float* mlpb = (const float*)d_in[18];
    const float* embW = (const float*)d_in[19];
    const float* embb = (const float*)d_in[20];

    float* out_s  = (float*)d_out;
    float* out_cr = out_s + (size_t)PREDL * BATCH * POSE;

    dim3 grid(BATCH / 64), block(256);
    hipLaunchKernelGGL(lstm_mfma, grid, block, 0, stream,
                       obs, eWih, eWhh, ebih, ebhh, dWih, dWhh, dbih, dbhh,
                       cWih, cWhh, cbih, cbhh, fcW, fcb, fccW, fccb,
                       mlpW, mlpb, embW, embb, out_s, out_cr);
}